// Round 1
// baseline (607.003 us; speedup 1.0000x reference)
//
#include <hip/hip_runtime.h>
#include <hip/hip_bf16.h>

// Problem constants (B=1)
#define SEQ   2048
#define DM    4096
#define NH    32
#define NKVH  8
#define HD    128
#define NQKV  6144
#define KOFF  4096
#define VOFF  5120
#define QLD   5120     // qkv row stride: V cols not materialized row-major
#define SCALE 0.08838834764831845f

typedef __attribute__((ext_vector_type(4))) float f32x4;
typedef __attribute__((ext_vector_type(8))) short short8;

__device__ __forceinline__ unsigned short f2bf(float f) {
  union { float f; unsigned int u; } v; v.f = f;
  unsigned int r = v.u + 0x7FFF + ((v.u >> 16) & 1);
  return (unsigned short)(r >> 16);
}
__device__ __forceinline__ float bf2f(unsigned short b) {
  union { unsigned int u; float f; } v; v.u = ((unsigned int)b) << 16;
  return v.f;
}

// async global->LDS, 16B per lane; LDS dest = wave-uniform base + lane*16
__device__ __forceinline__ void gld16(const unsigned short* g, unsigned short* l) {
  __builtin_amdgcn_global_load_lds(
      (const __attribute__((address_space(1))) unsigned int*)g,
      (__attribute__((address_space(3))) unsigned int*)l, 16, 0, 0);
}

// ---------------- fused prep: hs cast (blocks 0..8191) + weight transpose ----------------
__global__ __launch_bounds__(256) void prep(const float* __restrict__ hs,
                                            const float* __restrict__ wq,
                                            const float* __restrict__ wk,
                                            const float* __restrict__ wv,
                                            const float* __restrict__ wo,
                                            unsigned short* __restrict__ hsb,
                                            unsigned short* __restrict__ wqkvT,
                                            unsigned short* __restrict__ woT) {
  __shared__ unsigned short t[64][68];
  const int bxg = blockIdx.x;
  const int tid = threadIdx.x;
  if (bxg < 8192) {                       // ---- cast hs fp32 -> bf16 ----
    size_t i = ((size_t)bxg * 256 + tid) * 4;
    float4 v = *(const float4*)(hs + i);
    ushort4 o;
    o.x = f2bf(v.x); o.y = f2bf(v.y); o.z = f2bf(v.z); o.w = f2bf(v.w);
    *(ushort4*)(hsb + i) = o;
    return;
  }
  // ---- weight transpose+cast, 64x64 tiles ----
  const int b  = bxg - 8192;
  const int bx = b % 160;
  const int k0 = (b / 160) * 64;
  const float* W; unsigned short* out; int N, n0, row_off;
  if (bx < 64)      { W = wq; out = wqkvT; N = 4096; n0 = bx * 64;        row_off = 0;    }
  else if (bx < 80) { W = wk; out = wqkvT; N = 1024; n0 = (bx - 64) * 64; row_off = 4096; }
  else if (bx < 96) { W = wv; out = wqkvT; N = 1024; n0 = (bx - 80) * 64; row_off = 5120; }
  else              { W = wo; out = woT;   N = 4096; n0 = (bx - 96) * 64; row_off = 0;    }

  const int lr = tid >> 4, lc = (tid & 15) * 4;
#pragma unroll
  for (int i = 0; i < 4; ++i) {
    float4 v = *(const float4*)&W[(size_t)(k0 + lr + i * 16) * N + n0 + lc];
    ushort4 u; u.x = f2bf(v.x); u.y = f2bf(v.y); u.z = f2bf(v.z); u.w = f2bf(v.w);
    *(ushort4*)&t[lr + i * 16][lc] = u;
  }
  __syncthreads();

  const int sn = tid >> 2, sk = (tid & 3) * 4;
#pragma unroll
  for (int i = 0; i < 4; ++i) {
    int kk = sk + i * 16;
    ushort4 u;
    u.x = t[kk + 0][sn]; u.y = t[kk + 1][sn];
    u.z = t[kk + 2][sn]; u.w = t[kk + 3][sn];
    *(ushort4*)&out[(size_t)(row_off + n0 + sn) * DM + k0 + kk] = u;
  }
}

// ---------------- GEMM: C[M,N] = A[M,K] @ Bt[N,K]^T -----------------------
// 8-phase 256-class template (learn_hip m194-m218 schedule, plain HIP):
//   512 threads = 8 waves (2M x 4N), BK=64, double-buffered LDS,
//   XOR chunk swizzle (c ^ (row&7)) applied to the gld16 *source* and the
//   ds_read offset (linear LDS dest, rule: both-sides-or-neither),
//   counted s_waitcnt vmcnt(LPT) -- next tile's loads stay in flight across
//   the whole compute of the current tile -- raw s_barrier (no vmcnt drain),
//   s_setprio(1) around each 16-MFMA cluster.
// BM=256: per-wave 128x64 output (MT=8). BM=128: per-wave 64x64 (MT=4).
// If vt != null, column-blocks with n0 >= VOFF write TRANSPOSED bf16 to
// vt[(col-VOFF)*SEQ + row] (V block), as before. ldc decouples C stride.
template <int BM, int BN>
__global__ __launch_bounds__(512, 2) void gemm8p(const unsigned short* __restrict__ A,
                                                 const unsigned short* __restrict__ Bt,
                                                 void* __restrict__ C,
                                                 unsigned short* __restrict__ vt,
                                                 int K, int ldc, int c_fp32) {
  constexpr int MT  = BM / 32;           // 16-row tiles per wave (WM=2)
  constexpr int LPT = (BM + BN) / 64;    // gld16 issues per wave per K-tile
  __shared__ __align__(16) unsigned short As[2][BM * 64];
  __shared__ __align__(16) unsigned short Bs[2][BN * 64];

  const int tid = threadIdx.x;
  // XCD-aware bijective block swizzle (grid size % 8 == 0 for both launches)
  const int nx = gridDim.x;
  int lin = blockIdx.y * nx + blockIdx.x;
  {
    const int q = (nx * (int)gridDim.y) >> 3;
    lin = (lin & 7) * q + (lin >> 3);
  }
  const int m0 = (lin / nx) * BM;
  const int n0 = (lin % nx) * BN;

  const int w    = tid >> 6;
  const int lane = tid & 63;
  const int l16  = lane & 15;
  const int quad = lane >> 4;
  const int wm   = w >> 2;
  const int wn   = w & 3;
  const int wr   = wm * (MT * 16);
  const int wc   = wn * 64;

  f32x4 acc[MT][4];
#pragma unroll
  for (int i = 0; i < MT; ++i)
#pragma unroll
    for (int j = 0; j < 4; ++j) acc[i][j] = (f32x4){0.f, 0.f, 0.f, 0.f};

  // staging: wave w call i covers rows i*64 + w*8 .. +8 of the tile.
  // lane l: row = base + (l>>3), phys 16B chunk = l&7; source fetches the
  // logical chunk (l&7) ^ (row&7)  (row&7 == l>>3 here) so that the linear
  // DMA write realizes the XOR-swizzled layout.
  const int r8 = lane >> 3;
  const int g  = (lane & 7) ^ r8;
  const unsigned short* sA = A  + (size_t)(m0 + w * 8 + r8) * K + g * 8;
  const unsigned short* sB = Bt + (size_t)(n0 + w * 8 + r8) * K + g * 8;

  const int NT = K >> 6;

  // frag-read swizzled chunk offsets (shorts): chunk (ks*4+quad) ^ (row&7),
  // and row&7 == l16&7 for all fragment rows (wr, mt*16 are 0 mod 8).
  const int sw  = l16 & 7;
  const int ck0 = (quad ^ sw) * 8;
  const int ck1 = ((4 + quad) ^ sw) * 8;
  const int arow = (wr + l16) * 64;
  const int brow = (wc + l16) * 64;

  // prologue: stage tile 0 into buffer 0
#pragma unroll
  for (int i = 0; i < BM / 64; ++i)
    gld16(sA + (size_t)i * 64 * K, &As[0][(i * 64 + w * 8) * 64]);
#pragma unroll
  for (int i = 0; i < BN / 64; ++i)
    gld16(sB + (size_t)i * 64 * K, &Bs[0][(i * 64 + w * 8) * 64]);

  for (int t = 0; t < NT; ++t) {
    const int cur = t & 1;
    if (t + 1 < NT) {
      // issue next tile's loads FIRST (they ride across this tile's compute),
      // then counted-wait for the current tile's loads only.
      const int ko = (t + 1) * 64;
#pragma unroll
      for (int i = 0; i < BM / 64; ++i)
        gld16(sA + (size_t)i * 64 * K + ko, &As[cur ^ 1][(i * 64 + w * 8) * 64]);
#pragma unroll
      for (int i = 0; i < BN / 64; ++i)
        gld16(sB + (size_t)i * 64 * K + ko, &Bs[cur ^ 1][(i * 64 + w * 8) * 64]);
      asm volatile("s_waitcnt vmcnt(%0)" :: "n"(LPT) : "memory");
    } else {
      asm volatile("s_waitcnt vmcnt(0)" ::: "memory");
    }
    __builtin_amdgcn_s_barrier();   // all waves' DMA for buf[cur] landed

#pragma unroll
    for (int ks = 0; ks < 2; ++ks) {
      const int ck = ks ? ck1 : ck0;
      short8 bfrag[4];
#pragma unroll
      for (int nt = 0; nt < 4; ++nt)
        bfrag[nt] = *(const short8*)&Bs[cur][brow + nt * 1024 + ck];
#pragma unroll
      for (int mh = 0; mh < MT / 4; ++mh) {
        short8 afrag[4];
#pragma unroll
        for (int mi = 0; mi < 4; ++mi)
          afrag[mi] = *(const short8*)&As[cur][arow + (mh * 4 + mi) * 1024 + ck];
        __builtin_amdgcn_s_barrier();         // phase alignment
        __builtin_amdgcn_s_setprio(1);
#pragma unroll
        for (int mi = 0; mi < 4; ++mi)
#pragma unroll
          for (int nt = 0; nt < 4; ++nt)
            acc[mh * 4 + mi][nt] = __builtin_amdgcn_mfma_f32_16x16x32_bf16(
                afrag[mi], bfrag[nt], acc[mh * 4 + mi][nt], 0, 0, 0);
        __builtin_amdgcn_s_setprio(0);
        __builtin_amdgcn_s_barrier();         // last one doubles as tile-end WAR fence
      }
    }
  }

  if (vt && n0 >= VOFF) {       // V block: transposed bf16 store vt[col][row]
#pragma unroll
    for (int mt = 0; mt < MT; ++mt)
#pragma unroll
      for (int nt = 0; nt < 4; ++nt) {
        int col  = (n0 - VOFF) + wc + nt * 16 + l16;
        int row0 = m0 + wr + mt * 16 + quad * 4;
        ushort4 ov;
        ov.x = f2bf(acc[mt][nt][0]); ov.y = f2bf(acc[mt][nt][1]);
        ov.z = f2bf(acc[mt][nt][2]); ov.w = f2bf(acc[mt][nt][3]);
        *(ushort4*)&vt[(size_t)col * SEQ + row0] = ov;
      }
  } else if (c_fp32) {
    float* Cf = (float*)C;
#pragma unroll
    for (int mt = 0; mt < MT; ++mt)
#pragma unroll
      for (int nt = 0; nt < 4; ++nt) {
        int col = n0 + wc + nt * 16 + l16;
#pragma unroll
        for (int r = 0; r < 4; ++r)
          Cf[(size_t)(m0 + wr + mt * 16 + quad * 4 + r) * ldc + col] = acc[mt][nt][r];
      }
  } else {
    unsigned short* Cb = (unsigned short*)C;
#pragma unroll
    for (int mt = 0; mt < MT; ++mt)
#pragma unroll
      for (int nt = 0; nt < 4; ++nt) {
        int col = n0 + wc + nt * 16 + l16;
#pragma unroll
        for (int r = 0; r < 4; ++r)
          Cb[(size_t)(m0 + wr + mt * 16 + quad * 4 + r) * ldc + col] = f2bf(acc[mt][nt][r]);
      }
  }
}

// ---------------- RoPE in-place on qkv (stride QLD), heads 0..39 = 32 q + 8 k ----------------
__global__ __launch_bounds__(256) void rope_kernel(unsigned short* __restrict__ QKV,
                                                   const float* __restrict__ cosb,
                                                   const float* __restrict__ sinb) {
  int idx = blockIdx.x * 256 + threadIdx.x;
  int i = idx & 63;
  int h = (idx >> 6) % 40;
  int s = idx / 2560;
  size_t base = (size_t)s * QLD + (size_t)h * 128;
  float q1 = bf2f(QKV[base + i]);
  float q2 = bf2f(QKV[base + i + 64]);
  float c1 = cosb[s * 128 + i],      s1 = sinb[s * 128 + i];
  float c2 = cosb[s * 128 + i + 64], s2 = sinb[s * 128 + i + 64];
  QKV[base + i]      = f2bf(q1 * c1 - q2 * s1);
  QKV[base + i + 64] = f2bf(q2 * c2 + q1 * s2);
}

// ---------------- flash attention: S^T formulation (QLD stride) ----------------
__global__ __launch_bounds__(256) void flash_attn(const unsigned short* __restrict__ QKV,
                                                  const unsigned short* __restrict__ Vt_g,
                                                  unsigned short* __restrict__ AO) {
  __shared__ unsigned short Ks[64 * 136];
  __shared__ unsigned short Vs[128 * 72];
  __shared__ unsigned short Ps[4][32 * 68];

  const int h   = blockIdx.x;
  const int qt  = (int)gridDim.y - 1 - (int)blockIdx.y;
  const int kvh = h >> 2;
  const int tid  = threadIdx.x;
  const int w    = tid >> 6;
  const int lane = tid & 63;
  const int l16  = lane & 15;
  const int quad = lane >> 4;
  const int q0   = qt * 128;
  const int qrow_w = q0 + w * 32;

  short8 qf[2][4];
#pragma unroll
  for (int ntq = 0; ntq < 2; ++ntq) {
    const unsigned short* qp = QKV + (size_t)(qrow_w + ntq * 16 + l16) * QLD + h * HD + quad * 8;
#pragma unroll
    for (int ks = 0; ks < 4; ++ks) qf[ntq][ks] = *(const short8*)(qp + ks * 32);
  }

  f32x4 o[8][2];
#pragma unroll
  for (int i = 0; i < 8; ++i) { o[i][0] = (f32x4){0,0,0,0}; o[i][1] = (f32x4){0,0,0,0}; }
  float m_i[2] = {-3.0e38f, -3.0e38f}, l_i[2] = {0.f, 0.f};

  const int kr = tid >> 2, kcol0 = (tid & 3) * 32;
  const int vr = tid >> 1, vcol0 = (tid & 1) * 32;
  const unsigned short* kbase = QKV + KOFF + (size_t)kvh * HD + kcol0;
  const unsigned short* vbase = Vt_g + ((size_t)kvh * HD + vr) * SEQ + vcol0;

  const int nch = qt * 2 + 2;
  for (int c = 0; c < nch; ++c) {
    const int kc = c * 64;
    short8 kv[4], vv[4];
#pragma unroll
    for (int u = 0; u < 4; ++u) kv[u] = *(const short8*)(kbase + (size_t)(kc + kr) * QLD + u * 8);
#pragma unroll
    for (int u = 0; u < 4; ++u) vv[u] = *(const short8*)(vbase + kc + u * 8);
    __syncthreads();
#pragma unroll
    for (int u = 0; u < 4; ++u) *(short8*)&Ks[kr * 136 + kcol0 + u * 8] = kv[u];
#pragma unroll
    for (int u = 0; u < 4; ++u) *(short8*)&Vs[vr * 72 + vcol0 + u * 8] = vv[u];
    __syncthreads();

    if (kc <= qrow_w + 31) {
      f32x4 st[4][2];
#pragma unroll
      for (int mt = 0; mt < 4; ++mt) { st[mt][0] = (f32x4){0,0,0,0}; st[mt][1] = (f32x4){0,0,0,0}; }
#pragma unroll
      for (int ks = 0; ks < 4; ++ks)
#pragma unroll
        for (int mt = 0; mt < 4; ++mt) {
          short8 ak = *(const short8*)&Ks[(mt * 16 + l16) * 136 + ks * 32 + quad * 8];
          st[mt][0] = __builtin_amdgcn_mfma_f32_16x16x32_bf16(ak, qf[0][ks], st[mt][0], 0, 0, 0);
          st[mt][1] = __builtin_amdgcn_mfma_f32_16x16x32_bf16(ak, qf[1][ks], st[mt][1], 0, 0, 0);
        }

      float sc[4][2][4];
#pragma unroll
      for (int mt = 0; mt < 4; ++mt)
#pragma unroll
        for (int ntq = 0; ntq < 2; ++ntq) {
          int qr = qrow_w + ntq * 16 + l16;
#pragma unroll
          for (int r = 0; r < 4; ++r) {
            int key = kc + mt * 16 + quad * 4 + r;
            float v = st[mt][ntq][r] * SCALE;
            sc[mt][ntq][r] = (key <= qr) ? v : -__builtin_inff();
          }
        }
      float mx[2] = {-__builtin_inff(), -__builtin_inff()};
#pragma unroll
      for (int mt = 0; mt < 4; ++mt)
#pragma unroll
        for (int ntq = 0; ntq < 2; ++ntq)
#pragma unroll
          for (int r = 0; r < 4; ++r) mx[ntq] = fmaxf(mx[ntq], sc[mt][ntq][r]);
#pragma unroll
      for (int ntq = 0; ntq < 2; ++ntq) {
        mx[ntq] = fmaxf(mx[ntq], __shfl_xor(mx[ntq], 16, 64));
        mx[ntq] = fmaxf(mx[ntq], __shfl_xor(mx[ntq], 32, 64));
      }
      float al[2], mn[2];
#pragma unroll
      for (int ntq = 0; ntq < 2; ++ntq) {
        mn[ntq] = fmaxf(m_i[ntq], mx[ntq]);
        al[ntq] = __expf(m_i[ntq] - mn[ntq]);
        m_i[ntq] = mn[ntq];
      }

      float rs[2] = {0.f, 0.f};
      unsigned short* psw = &Ps[w][0];
#pragma unroll
      for (int mt = 0; mt < 4; ++mt)
#pragma unroll
        for (int ntq = 0; ntq < 2; ++ntq) {
          float p0 = __expf(sc[mt][ntq][0] - mn[ntq]);
          float p1 = __expf(sc[mt][ntq][1] - mn[ntq]);
          float p2 = __expf(sc[mt][ntq][2] - mn[ntq]);
          float p3 = __expf(sc[mt][ntq][3] - mn[ntq]);
          rs[ntq] += (p0 + p1) + (p2 + p3);
          ushort4 pk; pk.x = f2bf(p0); pk.y = f2bf(p1); pk.z = f2bf(p2); pk.w = f2bf(p3);
          *(ushort4*)&psw[(ntq * 16 + l16) * 68 + mt * 16 + quad * 4] = pk;
        }
#pragma unroll
      for (int ntq = 0; ntq < 2; ++ntq) {
        rs[ntq] += __shfl_xor(rs[ntq], 16, 64);
        rs[ntq] += __shfl_xor(rs[ntq], 32, 64);
        l_i[ntq] = l_i[ntq] * al[ntq] + rs[ntq];
      }
#pragma unroll
      for (int i = 0; i < 8; ++i) {
        o[i][0][0] *= al[0]; o[i][0][1] *= al[0]; o[i][0][2] *= al[0]; o[i][0][3] *= al[0];
        o[i][1][0] *= al[1]; o[i][1][1] *= al[1]; o[i][1][2] *= al[1]; o[i][1][3] *= al[1];
      }

#pragma unroll
      for (int ks = 0; ks < 2; ++ks) {
        short8 bp[2];
#pragma unroll
        for (int ntq = 0; ntq < 2; ++ntq) {
          union { ushort4 h[2]; short8 v; } u;
          const unsigned short* pp = &psw[(ntq * 16 + l16) * 68 + ks * 32 + quad * 8];
          u.h[0] = *(const ushort4*)(pp);
          u.h[1] = *(const ushort4*)(pp + 4);
          bp[ntq] = u.v;
        }
#pragma unroll
        for (int mt = 0; mt < 8; ++mt) {
          short8 av = *(const short8*)&Vs[(mt * 16 + l16) * 72 + ks * 32 + quad * 8];
          o[mt][0] = __builtin_amdgcn_mfma_f32_16x16x32_bf16(av, bp[0], o[mt][0], 0, 0, 0);
          o[mt][1] = __builtin_amdgcn_mfma_f32_16x16x32_bf16(av, bp[1], o[mt][1], 0, 0, 0);
        }
      }
    }
  }

  float inv[2] = {1.0f / l_i[0], 1.0f / l_i[1]};
#pragma unroll
  for (int mt = 0; mt < 8; ++mt)
#pragma unroll
    for (int ntq = 0; ntq < 2; ++ntq) {
      int qr = qrow_w + ntq * 16 + l16;
      int col = h * HD + mt * 16 + quad * 4;
      ushort4 ov;
      ov.x = f2bf(o[mt][ntq][0] * inv[ntq]);
      ov.y = f2bf(o[mt][ntq][1] * inv[ntq]);
      ov.z = f2bf(o[mt][ntq][2] * inv[ntq]);
      ov.w = f2bf(o[mt][ntq][3] * inv[ntq]);
      *(ushort4*)&AO[(size_t)qr * DM + col] = ov;
    }
}

extern "C" void kernel_launch(void* const* d_in, const int* in_sizes, int n_in,
                              void* d_out, int out_size, void* d_ws, size_t ws_size,
                              hipStream_t stream) {
  const float* hs   = (const float*)d_in[0];
  const float* cosb = (const float*)d_in[1];
  const float* sinb = (const float*)d_in[2];
  // d_in[3] attention_mask: all ones -> causal-only
  const float* wq = (const float*)d_in[4];
  const float* wk = (const float*)d_in[5];
  const float* wv = (const float*)d_in[6];
  const float* wo = (const float*)d_in[7];
  float* out = (float*)d_out;

  char* ws = (char*)d_ws;
  unsigned short* hsb   = (unsigned short*)(ws);                 // 16 MB
  unsigned short* wqkvT = (unsigned short*)(ws + (16u << 20));   // 48 MB
  unsigned short* woT   = (unsigned short*)(ws + (64u << 20));   // 32 MB
  unsigned short* qkv   = (unsigned short*)(ws + (96u << 20));   // 20 MB (2048 x 5120, Q+K only)
  unsigned short* ao    = (unsigned short*)(ws + (116u << 20));  // 16 MB
  unsigned short* Vt_g  = (unsigned short*)(ws + (132u << 20));  // 4 MB (distinct: gemm writes it while reading hsb)

  prep<<<8192 + 160 * 64, 256, 0, stream>>>(hs, wq, wk, wv, wo, hsb, wqkvT, woT);
  // QKV projection: 256x256 tiles, grid 24x8 = 192 blocks (%8==0 for XCD swizzle)
  gemm8p<256, 256><<<dim3(NQKV / 256, SEQ / 256), 512, 0, stream>>>(
      hsb, wqkvT, qkv, Vt_g, DM, QLD, 0);
  rope_kernel<<<20480, 256, 0, stream>>>(qkv, cosb, sinb);
  flash_attn<<<dim3(NH, SEQ / 128), 256, 0, stream>>>(qkv, Vt_g, ao);
  // output projection: 128x256 tiles, grid 16x16 = 256 blocks = 1/CU
  gemm8p<128, 256><<<dim3(DM / 256, SEQ / 128), 512, 0, stream>>>(
      ao, woT, out, nullptr, DM, DM, 1);
}

// Round 2
// 564.465 us; speedup vs baseline: 1.0754x; 1.0754x over previous
//
#include <hip/hip_runtime.h>
#include <hip/hip_bf16.h>

// Problem constants (B=1)
#define SEQ   2048
#define DM    4096
#define NH    32
#define NKVH  8
#define HD    128
#define NQKV  6144
#define KOFF  4096
#define VOFF  5120
#define QLD   5120     // qkv row stride: V cols not materialized row-major
#define SCALE 0.08838834764831845f

typedef __attribute__((ext_vector_type(4))) float f32x4;
typedef __attribute__((ext_vector_type(8))) short short8;

__device__ __forceinline__ unsigned short f2bf(float f) {
  union { float f; unsigned int u; } v; v.f = f;
  unsigned int r = v.u + 0x7FFF + ((v.u >> 16) & 1);
  return (unsigned short)(r >> 16);
}
__device__ __forceinline__ float bf2f(unsigned short b) {
  union { unsigned int u; float f; } v; v.u = ((unsigned int)b) << 16;
  return v.f;
}

// async global->LDS, 16B per lane; LDS dest = wave-uniform base + lane*16
__device__ __forceinline__ void gld16(const unsigned short* g, unsigned short* l) {
  __builtin_amdgcn_global_load_lds(
      (const __attribute__((address_space(1))) unsigned int*)g,
      (__attribute__((address_space(3))) unsigned int*)l, 16, 0, 0);
}

// ---------------- fused prep: hs cast (blocks 0..8191) + weight transpose ----------------
__global__ __launch_bounds__(256) void prep(const float* __restrict__ hs,
                                            const float* __restrict__ wq,
                                            const float* __restrict__ wk,
                                            const float* __restrict__ wv,
                                            const float* __restrict__ wo,
                                            unsigned short* __restrict__ hsb,
                                            unsigned short* __restrict__ wqkvT,
                                            unsigned short* __restrict__ woT) {
  __shared__ unsigned short t[64][68];
  const int bxg = blockIdx.x;
  const int tid = threadIdx.x;
  if (bxg < 8192) {                       // ---- cast hs fp32 -> bf16 ----
    size_t i = ((size_t)bxg * 256 + tid) * 4;
    float4 v = *(const float4*)(hs + i);
    ushort4 o;
    o.x = f2bf(v.x); o.y = f2bf(v.y); o.z = f2bf(v.z); o.w = f2bf(v.w);
    *(ushort4*)(hsb + i) = o;
    return;
  }
  // ---- weight transpose+cast, 64x64 tiles ----
  const int b  = bxg - 8192;
  const int bx = b % 160;
  const int k0 = (b / 160) * 64;
  const float* W; unsigned short* out; int N, n0, row_off;
  if (bx < 64)      { W = wq; out = wqkvT; N = 4096; n0 = bx * 64;        row_off = 0;    }
  else if (bx < 80) { W = wk; out = wqkvT; N = 1024; n0 = (bx - 64) * 64; row_off = 4096; }
  else if (bx < 96) { W = wv; out = wqkvT; N = 1024; n0 = (bx - 80) * 64; row_off = 5120; }
  else              { W = wo; out = woT;   N = 4096; n0 = (bx - 96) * 64; row_off = 0;    }

  const int lr = tid >> 4, lc = (tid & 15) * 4;
#pragma unroll
  for (int i = 0; i < 4; ++i) {
    float4 v = *(const float4*)&W[(size_t)(k0 + lr + i * 16) * N + n0 + lc];
    ushort4 u; u.x = f2bf(v.x); u.y = f2bf(v.y); u.z = f2bf(v.z); u.w = f2bf(v.w);
    *(ushort4*)&t[lr + i * 16][lc] = u;
  }
  __syncthreads();

  const int sn = tid >> 2, sk = (tid & 3) * 4;
#pragma unroll
  for (int i = 0; i < 4; ++i) {
    int kk = sk + i * 16;
    ushort4 u;
    u.x = t[kk + 0][sn]; u.y = t[kk + 1][sn];
    u.z = t[kk + 2][sn]; u.w = t[kk + 3][sn];
    *(ushort4*)&out[(size_t)(row_off + n0 + sn) * DM + k0 + kk] = u;
  }
}

// ---------------- GEMM: C[M,N] = A[M,K] @ Bt[N,K]^T -----------------------
// 8-phase 256-class template (m194-m218), with the R1 defect fixed:
//   K-loop unrolled x2 with FOUR separate __shared__ arrays so every LDS
//   access has a compile-time object identity. With the runtime-indexed
//   As[cur] of R1, the compiler's waitcnt pass could not disambiguate the
//   just-issued prefetch from the drained buffer and inserted vmcnt(0)
//   before the fragment reads -> ~900cy HBM-latency stall per K-tile
//   (measured: MfmaUtil 21.6%, 194us). Constant buffer identities make the
//   compiler's inserted waits >= LPT (free); the explicit pre-barrier
//   vmcnt(LPT) provides the cross-wave visibility guarantee.
// Schedule per K-tile: stage next tile -> vmcnt(LPT) -> barrier ->
//   phases of {ds_read frags; barrier; lgkmcnt(0); sched_barrier;
//   setprio(1); 16 MFMA; setprio(0); barrier}.
template <int BM, int BN>
__global__ __launch_bounds__(512, 2) void gemm8p(const unsigned short* __restrict__ A,
                                                 const unsigned short* __restrict__ Bt,
                                                 void* __restrict__ C,
                                                 unsigned short* __restrict__ vt,
                                                 int K, int ldc, int c_fp32) {
  constexpr int MT  = BM / 32;           // 16-row tiles per wave (WM=2)
  constexpr int LPT = (BM + BN) / 64;    // gld16 issues per wave per K-tile
  __shared__ __align__(16) unsigned short As0[BM * 64];
  __shared__ __align__(16) unsigned short As1[BM * 64];
  __shared__ __align__(16) unsigned short Bs0[BN * 64];
  __shared__ __align__(16) unsigned short Bs1[BN * 64];

  const int tid = threadIdx.x;
  // XCD-aware bijective swizzle, column-grouped: each XCD owns a contiguous
  // run of same-N-panel blocks -> its 2MB B-panel stays resident in its L2.
  const int nx = gridDim.x;
  const int ny = gridDim.y;
  int lin = blockIdx.y * nx + blockIdx.x;
  {
    const int q = (nx * ny) >> 3;        // grid % 8 == 0 for both launches
    lin = (lin & 7) * q + (lin >> 3);
  }
  const int n0 = (lin / ny) * BN;
  const int m0 = (lin % ny) * BM;

  const int w    = tid >> 6;
  const int lane = tid & 63;
  const int l16  = lane & 15;
  const int quad = lane >> 4;
  const int wm   = w >> 2;
  const int wn   = w & 3;
  const int wr   = wm * (MT * 16);
  const int wc   = wn * 64;

  f32x4 acc[MT][4];
#pragma unroll
  for (int i = 0; i < MT; ++i)
#pragma unroll
    for (int j = 0; j < 4; ++j) acc[i][j] = (f32x4){0.f, 0.f, 0.f, 0.f};

  // staging: wave w call i covers rows i*64 + w*8 .. +8 of the tile.
  // lane l: row = base + (l>>3), phys 16B chunk = l&7; source fetches the
  // logical chunk (l&7) ^ (row&7) so the linear DMA realizes the XOR layout.
  const int r8 = lane >> 3;
  const int g  = (lane & 7) ^ r8;
  const unsigned short* sA = A  + (size_t)(m0 + w * 8 + r8) * K + g * 8;
  const unsigned short* sB = Bt + (size_t)(n0 + w * 8 + r8) * K + g * 8;

  const int NT = K >> 6;                 // K=4096 -> 64 (even; loop steps 2)

  // frag-read swizzled chunk offsets (shorts): chunk (ks*4+quad) ^ (row&7);
  // row&7 == l16&7 for all fragment rows (wr, mt*16 are 0 mod 8).
  const int sw  = l16 & 7;
  const int ck0 = (quad ^ sw) * 8;
  const int ck1 = ((4 + quad) ^ sw) * 8;
  const int arow = (wr + l16) * 64;
  const int brow = (wc + l16) * 64;

#define STG(AS, BS, ko)                                                        \
  do {                                                                         \
    _Pragma("unroll") for (int i = 0; i < BM / 64; ++i)                        \
        gld16(sA + (size_t)i * 64 * K + (ko), &AS[(i * 64 + w * 8) * 64]);     \
    _Pragma("unroll") for (int i = 0; i < BN / 64; ++i)                        \
        gld16(sB + (size_t)i * 64 * K + (ko), &BS[(i * 64 + w * 8) * 64]);     \
  } while (0)

#define CMP(AS, BS)                                                            \
  do {                                                                         \
    _Pragma("unroll") for (int ks = 0; ks < 2; ++ks) {                         \
      const int ck = ks ? ck1 : ck0;                                           \
      short8 bfrag[4];                                                         \
      _Pragma("unroll") for (int nt = 0; nt < 4; ++nt)                         \
          bfrag[nt] = *(const short8*)&BS[brow + nt * 1024 + ck];              \
      _Pragma("unroll") for (int mh = 0; mh < MT / 4; ++mh) {                  \
        short8 afrag[4];                                                       \
        _Pragma("unroll") for (int mi = 0; mi < 4; ++mi)                       \
            afrag[mi] = *(const short8*)&AS[arow + (mh * 4 + mi) * 1024 + ck]; \
        __builtin_amdgcn_s_barrier();                                          \
        asm volatile("s_waitcnt lgkmcnt(0)" ::: "memory");                     \
        __builtin_amdgcn_sched_barrier(0);                                     \
        __builtin_amdgcn_s_setprio(1);                                         \
        _Pragma("unroll") for (int mi = 0; mi < 4; ++mi)                       \
            _Pragma("unroll") for (int nt = 0; nt < 4; ++nt)                   \
                acc[mh * 4 + mi][nt] = __builtin_amdgcn_mfma_f32_16x16x32_bf16(\
                    afrag[mi], bfrag[nt], acc[mh * 4 + mi][nt], 0, 0, 0);      \
        __builtin_amdgcn_s_setprio(0);                                         \
        __builtin_amdgcn_s_barrier();                                          \
      }                                                                        \
    }                                                                          \
  } while (0)

  // prologue: stage tile 0 into buffer 0
  STG(As0, Bs0, 0);

  for (int t = 0; t < NT; t += 2) {
    // ---- half A: compute buf0, prefetch tile t+1 into buf1 ----
    STG(As1, Bs1, (size_t)(t + 1) * 64);           // t+1 <= NT-1 always
    asm volatile("s_waitcnt vmcnt(%0)" :: "n"(LPT) : "memory");
    __builtin_amdgcn_s_barrier();                  // buf0 DMA visible block-wide
    CMP(As0, Bs0);                                 // trailing barrier: buf0 reads done
    // ---- half B: compute buf1, prefetch tile t+2 into buf0 ----
    if (t + 2 < NT) {
      STG(As0, Bs0, (size_t)(t + 2) * 64);
      asm volatile("s_waitcnt vmcnt(%0)" :: "n"(LPT) : "memory");
    } else {
      asm volatile("s_waitcnt vmcnt(0)" ::: "memory");
    }
    __builtin_amdgcn_s_barrier();                  // buf1 DMA visible block-wide
    CMP(As1, Bs1);                                 // trailing barrier: buf1 reads done
  }
#undef STG
#undef CMP

  if (vt && n0 >= VOFF) {       // V block: transposed bf16 store vt[col][row]
#pragma unroll
    for (int mt = 0; mt < MT; ++mt)
#pragma unroll
      for (int nt = 0; nt < 4; ++nt) {
        int col  = (n0 - VOFF) + wc + nt * 16 + l16;
        int row0 = m0 + wr + mt * 16 + quad * 4;
        ushort4 ov;
        ov.x = f2bf(acc[mt][nt][0]); ov.y = f2bf(acc[mt][nt][1]);
        ov.z = f2bf(acc[mt][nt][2]); ov.w = f2bf(acc[mt][nt][3]);
        *(ushort4*)&vt[(size_t)col * SEQ + row0] = ov;
      }
  } else if (c_fp32) {
    float* Cf = (float*)C;
#pragma unroll
    for (int mt = 0; mt < MT; ++mt)
#pragma unroll
      for (int nt = 0; nt < 4; ++nt) {
        int col = n0 + wc + nt * 16 + l16;
#pragma unroll
        for (int r = 0; r < 4; ++r)
          Cf[(size_t)(m0 + wr + mt * 16 + quad * 4 + r) * ldc + col] = acc[mt][nt][r];
      }
  } else {
    unsigned short* Cb = (unsigned short*)C;
#pragma unroll
    for (int mt = 0; mt < MT; ++mt)
#pragma unroll
      for (int nt = 0; nt < 4; ++nt) {
        int col = n0 + wc + nt * 16 + l16;
#pragma unroll
        for (int r = 0; r < 4; ++r)
          Cb[(size_t)(m0 + wr + mt * 16 + quad * 4 + r) * ldc + col] = f2bf(acc[mt][nt][r]);
      }
  }
}

// ---------------- RoPE in-place on qkv (stride QLD), heads 0..39 = 32 q + 8 k ----------------
__global__ __launch_bounds__(256) void rope_kernel(unsigned short* __restrict__ QKV,
                                                   const float* __restrict__ cosb,
                                                   const float* __restrict__ sinb) {
  int idx = blockIdx.x * 256 + threadIdx.x;
  int i = idx & 63;
  int h = (idx >> 6) % 40;
  int s = idx / 2560;
  size_t base = (size_t)s * QLD + (size_t)h * 128;
  float q1 = bf2f(QKV[base + i]);
  float q2 = bf2f(QKV[base + i + 64]);
  float c1 = cosb[s * 128 + i],      s1 = sinb[s * 128 + i];
  float c2 = cosb[s * 128 + i + 64], s2 = sinb[s * 128 + i + 64];
  QKV[base + i]      = f2bf(q1 * c1 - q2 * s1);
  QKV[base + i + 64] = f2bf(q2 * c2 + q1 * s2);
}

// ---------------- flash attention: S^T formulation (QLD stride) ----------------
__global__ __launch_bounds__(256) void flash_attn(const unsigned short* __restrict__ QKV,
                                                  const unsigned short* __restrict__ Vt_g,
                                                  unsigned short* __restrict__ AO) {
  __shared__ unsigned short Ks[64 * 136];
  __shared__ unsigned short Vs[128 * 72];
  __shared__ unsigned short Ps[4][32 * 68];

  const int h   = blockIdx.x;
  const int qt  = (int)gridDim.y - 1 - (int)blockIdx.y;
  const int kvh = h >> 2;
  const int tid  = threadIdx.x;
  const int w    = tid >> 6;
  const int lane = tid & 63;
  const int l16  = lane & 15;
  const int quad = lane >> 4;
  const int q0   = qt * 128;
  const int qrow_w = q0 + w * 32;

  short8 qf[2][4];
#pragma unroll
  for (int ntq = 0; ntq < 2; ++ntq) {
    const unsigned short* qp = QKV + (size_t)(qrow_w + ntq * 16 + l16) * QLD + h * HD + quad * 8;
#pragma unroll
    for (int ks = 0; ks < 4; ++ks) qf[ntq][ks] = *(const short8*)(qp + ks * 32);
  }

  f32x4 o[8][2];
#pragma unroll
  for (int i = 0; i < 8; ++i) { o[i][0] = (f32x4){0,0,0,0}; o[i][1] = (f32x4){0,0,0,0}; }
  float m_i[2] = {-3.0e38f, -3.0e38f}, l_i[2] = {0.f, 0.f};

  const int kr = tid >> 2, kcol0 = (tid & 3) * 32;
  const int vr = tid >> 1, vcol0 = (tid & 1) * 32;
  const unsigned short* kbase = QKV + KOFF + (size_t)kvh * HD + kcol0;
  const unsigned short* vbase = Vt_g + ((size_t)kvh * HD + vr) * SEQ + vcol0;

  const int nch = qt * 2 + 2;
  for (int c = 0; c < nch; ++c) {
    const int kc = c * 64;
    short8 kv[4], vv[4];
#pragma unroll
    for (int u = 0; u < 4; ++u) kv[u] = *(const short8*)(kbase + (size_t)(kc + kr) * QLD + u * 8);
#pragma unroll
    for (int u = 0; u < 4; ++u) vv[u] = *(const short8*)(vbase + kc + u * 8);
    __syncthreads();
#pragma unroll
    for (int u = 0; u < 4; ++u) *(short8*)&Ks[kr * 136 + kcol0 + u * 8] = kv[u];
#pragma unroll
    for (int u = 0; u < 4; ++u) *(short8*)&Vs[vr * 72 + vcol0 + u * 8] = vv[u];
    __syncthreads();

    if (kc <= qrow_w + 31) {
      f32x4 st[4][2];
#pragma unroll
      for (int mt = 0; mt < 4; ++mt) { st[mt][0] = (f32x4){0,0,0,0}; st[mt][1] = (f32x4){0,0,0,0}; }
#pragma unroll
      for (int ks = 0; ks < 4; ++ks)
#pragma unroll
        for (int mt = 0; mt < 4; ++mt) {
          short8 ak = *(const short8*)&Ks[(mt * 16 + l16) * 136 + ks * 32 + quad * 8];
          st[mt][0] = __builtin_amdgcn_mfma_f32_16x16x32_bf16(ak, qf[0][ks], st[mt][0], 0, 0, 0);
          st[mt][1] = __builtin_amdgcn_mfma_f32_16x16x32_bf16(ak, qf[1][ks], st[mt][1], 0, 0, 0);
        }

      float sc[4][2][4];
#pragma unroll
      for (int mt = 0; mt < 4; ++mt)
#pragma unroll
        for (int ntq = 0; ntq < 2; ++ntq) {
          int qr = qrow_w + ntq * 16 + l16;
#pragma unroll
          for (int r = 0; r < 4; ++r) {
            int key = kc + mt * 16 + quad * 4 + r;
            float v = st[mt][ntq][r] * SCALE;
            sc[mt][ntq][r] = (key <= qr) ? v : -__builtin_inff();
          }
        }
      float mx[2] = {-__builtin_inff(), -__builtin_inff()};
#pragma unroll
      for (int mt = 0; mt < 4; ++mt)
#pragma unroll
        for (int ntq = 0; ntq < 2; ++ntq)
#pragma unroll
          for (int r = 0; r < 4; ++r) mx[ntq] = fmaxf(mx[ntq], sc[mt][ntq][r]);
#pragma unroll
      for (int ntq = 0; ntq < 2; ++ntq) {
        mx[ntq] = fmaxf(mx[ntq], __shfl_xor(mx[ntq], 16, 64));
        mx[ntq] = fmaxf(mx[ntq], __shfl_xor(mx[ntq], 32, 64));
      }
      float al[2], mn[2];
#pragma unroll
      for (int ntq = 0; ntq < 2; ++ntq) {
        mn[ntq] = fmaxf(m_i[ntq], mx[ntq]);
        al[ntq] = __expf(m_i[ntq] - mn[ntq]);
        m_i[ntq] = mn[ntq];
      }

      float rs[2] = {0.f, 0.f};
      unsigned short* psw = &Ps[w][0];
#pragma unroll
      for (int mt = 0; mt < 4; ++mt)
#pragma unroll
        for (int ntq = 0; ntq < 2; ++ntq) {
          float p0 = __expf(sc[mt][ntq][0] - mn[ntq]);
          float p1 = __expf(sc[mt][ntq][1] - mn[ntq]);
          float p2 = __expf(sc[mt][ntq][2] - mn[ntq]);
          float p3 = __expf(sc[mt][ntq][3] - mn[ntq]);
          rs[ntq] += (p0 + p1) + (p2 + p3);
          ushort4 pk; pk.x = f2bf(p0); pk.y = f2bf(p1); pk.z = f2bf(p2); pk.w = f2bf(p3);
          *(ushort4*)&psw[(ntq * 16 + l16) * 68 + mt * 16 + quad * 4] = pk;
        }
#pragma unroll
      for (int ntq = 0; ntq < 2; ++ntq) {
        rs[ntq] += __shfl_xor(rs[ntq], 16, 64);
        rs[ntq] += __shfl_xor(rs[ntq], 32, 64);
        l_i[ntq] = l_i[ntq] * al[ntq] + rs[ntq];
      }
#pragma unroll
      for (int i = 0; i < 8; ++i) {
        o[i][0][0] *= al[0]; o[i][0][1] *= al[0]; o[i][0][2] *= al[0]; o[i][0][3] *= al[0];
        o[i][1][0] *= al[1]; o[i][1][1] *= al[1]; o[i][1][2] *= al[1]; o[i][1][3] *= al[1];
      }

#pragma unroll
      for (int ks = 0; ks < 2; ++ks) {
        short8 bp[2];
#pragma unroll
        for (int ntq = 0; ntq < 2; ++ntq) {
          union { ushort4 h[2]; short8 v; } u;
          const unsigned short* pp = &psw[(ntq * 16 + l16) * 68 + ks * 32 + quad * 8];
          u.h[0] = *(const ushort4*)(pp);
          u.h[1] = *(const ushort4*)(pp + 4);
          bp[ntq] = u.v;
        }
#pragma unroll
        for (int mt = 0; mt < 8; ++mt) {
          short8 av = *(const short8*)&Vs[(mt * 16 + l16) * 72 + ks * 32 + quad * 8];
          o[mt][0] = __builtin_amdgcn_mfma_f32_16x16x32_bf16(av, bp[0], o[mt][0], 0, 0, 0);
          o[mt][1] = __builtin_amdgcn_mfma_f32_16x16x32_bf16(av, bp[1], o[mt][1], 0, 0, 0);
        }
      }
    }
  }

  float inv[2] = {1.0f / l_i[0], 1.0f / l_i[1]};
#pragma unroll
  for (int mt = 0; mt < 8; ++mt)
#pragma unroll
    for (int ntq = 0; ntq < 2; ++ntq) {
      int qr = qrow_w + ntq * 16 + l16;
      int col = h * HD + mt * 16 + quad * 4;
      ushort4 ov;
      ov.x = f2bf(o[mt][ntq][0] * inv[ntq]);
      ov.y = f2bf(o[mt][ntq][1] * inv[ntq]);
      ov.z = f2bf(o[mt][ntq][2] * inv[ntq]);
      ov.w = f2bf(o[mt][ntq][3] * inv[ntq]);
      *(ushort4*)&AO[(size_t)qr * DM + col] = ov;
    }
}

extern "C" void kernel_launch(void* const* d_in, const int* in_sizes, int n_in,
                              void* d_out, int out_size, void* d_ws, size_t ws_size,
                              hipStream_t stream) {
  const float* hs   = (const float*)d_in[0];
  const float* cosb = (const float*)d_in[1];
  const float* sinb = (const float*)d_in[2];
  // d_in[3] attention_mask: all ones -> causal-only
  const float* wq = (const float*)d_in[4];
  const float* wk = (const float*)d_in[5];
  const float* wv = (const float*)d_in[6];
  const float* wo = (const float*)d_in[7];
  float* out = (float*)d_out;

  char* ws = (char*)d_ws;
  unsigned short* hsb   = (unsigned short*)(ws);                 // 16 MB
  unsigned short* wqkvT = (unsigned short*)(ws + (16u << 20));   // 48 MB
  unsigned short* woT   = (unsigned short*)(ws + (64u << 20));   // 32 MB
  unsigned short* qkv   = (unsigned short*)(ws + (96u << 20));   // 20 MB (2048 x 5120, Q+K only)
  unsigned short* ao    = (unsigned short*)(ws + (116u << 20));  // 16 MB
  unsigned short* Vt_g  = (unsigned short*)(ws + (132u << 20));  // 4 MB (distinct: gemm writes it while reading hsb)

  prep<<<8192 + 160 * 64, 256, 0, stream>>>(hs, wq, wk, wv, wo, hsb, wqkvT, woT);
  // QKV projection: 256x256 tiles, grid 24x8 = 192 blocks (%8==0 for XCD swizzle)
  gemm8p<256, 256><<<dim3(NQKV / 256, SEQ / 256), 512, 0, stream>>>(
      hsb, wqkvT, qkv, Vt_g, DM, QLD, 0);
  rope_kernel<<<20480, 256, 0, stream>>>(qkv, cosb, sinb);
  flash_attn<<<dim3(NH, SEQ / 128), 256, 0, stream>>>(qkv, Vt_g, ao);
  // output projection: 128x256 tiles, grid 16x16 = 256 blocks = 1/CU
  gemm8p<128, 256><<<dim3(DM / 256, SEQ / 128), 512, 0, stream>>>(
      ao, woT, out, nullptr, DM, DM, 1);
}

// Round 3
// 529.030 us; speedup vs baseline: 1.1474x; 1.0670x over previous
//
#include <hip/hip_runtime.h>
#include <hip/hip_bf16.h>

// Problem constants (B=1)
#define SEQ   2048
#define DM    4096
#define NH    32
#define NKVH  8
#define HD    128
#define NQKV  6144
#define KOFF  4096
#define VOFF  5120
#define QLD   5120     // qkv row stride: V cols not materialized row-major
#define SCALE 0.08838834764831845f

typedef __attribute__((ext_vector_type(4))) float f32x4;
typedef __attribute__((ext_vector_type(8))) short short8;

__device__ __forceinline__ unsigned short f2bf(float f) {
  union { float f; unsigned int u; } v; v.f = f;
  unsigned int r = v.u + 0x7FFF + ((v.u >> 16) & 1);
  return (unsigned short)(r >> 16);
}
__device__ __forceinline__ float bf2f(unsigned short b) {
  union { unsigned int u; float f; } v; v.u = ((unsigned int)b) << 16;
  return v.f;
}

// async global->LDS, 16B per lane; LDS dest = wave-uniform base + lane*16
__device__ __forceinline__ void gld16(const unsigned short* g, unsigned short* l) {
  __builtin_amdgcn_global_load_lds(
      (const __attribute__((address_space(1))) unsigned int*)g,
      (__attribute__((address_space(3))) unsigned int*)l, 16, 0, 0);
}

// ---------------- fused prep: hs cast (blocks 0..8191) + weight transpose ----------------
__global__ __launch_bounds__(256) void prep(const float* __restrict__ hs,
                                            const float* __restrict__ wq,
                                            const float* __restrict__ wk,
                                            const float* __restrict__ wv,
                                            const float* __restrict__ wo,
                                            unsigned short* __restrict__ hsb,
                                            unsigned short* __restrict__ wqkvT,
                                            unsigned short* __restrict__ woT) {
  __shared__ unsigned short t[64][68];
  const int bxg = blockIdx.x;
  const int tid = threadIdx.x;
  if (bxg < 8192) {                       // ---- cast hs fp32 -> bf16 ----
    size_t i = ((size_t)bxg * 256 + tid) * 4;
    float4 v = *(const float4*)(hs + i);
    ushort4 o;
    o.x = f2bf(v.x); o.y = f2bf(v.y); o.z = f2bf(v.z); o.w = f2bf(v.w);
    *(ushort4*)(hsb + i) = o;
    return;
  }
  // ---- weight transpose+cast, 64x64 tiles ----
  const int b  = bxg - 8192;
  const int bx = b % 160;
  const int k0 = (b / 160) * 64;
  const float* W; unsigned short* out; int N, n0, row_off;
  if (bx < 64)      { W = wq; out = wqkvT; N = 4096; n0 = bx * 64;        row_off = 0;    }
  else if (bx < 80) { W = wk; out = wqkvT; N = 1024; n0 = (bx - 64) * 64; row_off = 4096; }
  else if (bx < 96) { W = wv; out = wqkvT; N = 1024; n0 = (bx - 80) * 64; row_off = 5120; }
  else              { W = wo; out = woT;   N = 4096; n0 = (bx - 96) * 64; row_off = 0;    }

  const int lr = tid >> 4, lc = (tid & 15) * 4;
#pragma unroll
  for (int i = 0; i < 4; ++i) {
    float4 v = *(const float4*)&W[(size_t)(k0 + lr + i * 16) * N + n0 + lc];
    ushort4 u; u.x = f2bf(v.x); u.y = f2bf(v.y); u.z = f2bf(v.z); u.w = f2bf(v.w);
    *(ushort4*)&t[lr + i * 16][lc] = u;
  }
  __syncthreads();

  const int sn = tid >> 2, sk = (tid & 3) * 4;
#pragma unroll
  for (int i = 0; i < 4; ++i) {
    int kk = sk + i * 16;
    ushort4 u;
    u.x = t[kk + 0][sn]; u.y = t[kk + 1][sn];
    u.z = t[kk + 2][sn]; u.w = t[kk + 3][sn];
    *(ushort4*)&out[(size_t)(row_off + n0 + sn) * DM + k0 + kk] = u;
  }
}

// ---------------- GEMM: C[M,N] = A[M,K] @ Bt[N,K]^T ----------------
// R5 config: 128x128 tile, BK=32, double-buffered gld16 (1 barrier/iter),
// coalesced staging (4 lanes per 64B row-slice), XOR k-block LDS swizzle.
// Proven 803 TF on this problem; the 256-class 8-phase port (R1/R2)
// measured SLOWER (630 TF: 1 block/CU kills cross-block overlap, and the
// per-phase lgkmcnt(0) serializes LDS latency against MFMA) -> reverted.
__global__ __launch_bounds__(256) void gemm_bt(const unsigned short* __restrict__ A,
                                               const unsigned short* __restrict__ Bt,
                                               void* __restrict__ C,
                                               unsigned short* __restrict__ vt,
                                               int M, int N, int K, int ldc, int c_fp32) {
  __shared__ unsigned short As[2][128 * 32];
  __shared__ unsigned short Bs[2][128 * 32];
  const int tid  = threadIdx.x;
  const int m0   = blockIdx.y * 128;
  const int n0   = blockIdx.x * 128;
  const int w    = tid >> 6;
  const int lane = tid & 63;
  const int l16  = lane & 15;
  const int quad = lane >> 4;
  const int wr   = (w >> 1) * 64;
  const int wc   = (w & 1) * 64;

  f32x4 acc[4][4];
#pragma unroll
  for (int i = 0; i < 4; ++i)
#pragma unroll
    for (int j = 0; j < 4; ++j) acc[i][j] = (f32x4){0.f, 0.f, 0.f, 0.f};

  const int sr  = lane >> 2;
  const int pb  = lane & 3;
  const int sws = (sr & 3) ^ ((sr >> 2) & 3);
  const int kb  = ((pb ^ sws) << 3);
  const unsigned short* ga0 = A  + (size_t)(m0 + w * 16 + sr) * K + kb;
  const unsigned short* ga1 = A  + (size_t)(m0 + 64 + w * 16 + sr) * K + kb;
  const unsigned short* gb0 = Bt + (size_t)(n0 + w * 16 + sr) * K + kb;
  const unsigned short* gb1 = Bt + (size_t)(n0 + 64 + w * 16 + sr) * K + kb;
  const int lofs0 = (w * 16) * 32;
  const int lofs1 = (64 + w * 16) * 32;

  const int swf  = (l16 & 3) ^ ((l16 >> 2) & 3);
  const int fcol = ((quad ^ swf) << 3);

  gld16(ga0, &As[0][lofs0]);
  gld16(ga1, &As[0][lofs1]);
  gld16(gb0, &Bs[0][lofs0]);
  gld16(gb1, &Bs[0][lofs1]);

  int p = 0;
  for (int k0 = 0; k0 < K; k0 += 32) {
    __syncthreads();            // drains vmcnt -> buf p visible; buf p^1 WAR-safe
    if (k0 + 32 < K) {
      gld16(ga0 + k0 + 32, &As[p ^ 1][lofs0]);
      gld16(ga1 + k0 + 32, &As[p ^ 1][lofs1]);
      gld16(gb0 + k0 + 32, &Bs[p ^ 1][lofs0]);
      gld16(gb1 + k0 + 32, &Bs[p ^ 1][lofs1]);
    }
    short8 af[4], bfr[4];
#pragma unroll
    for (int mt = 0; mt < 4; ++mt)
      af[mt] = *(const short8*)&As[p][(wr + mt * 16 + l16) * 32 + fcol];
#pragma unroll
    for (int nt = 0; nt < 4; ++nt)
      bfr[nt] = *(const short8*)&Bs[p][(wc + nt * 16 + l16) * 32 + fcol];
#pragma unroll
    for (int mt = 0; mt < 4; ++mt)
#pragma unroll
      for (int nt = 0; nt < 4; ++nt)
        acc[mt][nt] = __builtin_amdgcn_mfma_f32_16x16x32_bf16(af[mt], bfr[nt], acc[mt][nt], 0, 0, 0);
    p ^= 1;
  }

  if (vt && n0 >= VOFF) {       // V block: transposed bf16 store vt[col][row]
#pragma unroll
    for (int mt = 0; mt < 4; ++mt)
#pragma unroll
      for (int nt = 0; nt < 4; ++nt) {
        int col  = (n0 - VOFF) + wc + nt * 16 + l16;
        int row0 = m0 + wr + mt * 16 + quad * 4;
        ushort4 ov;
        ov.x = f2bf(acc[mt][nt][0]); ov.y = f2bf(acc[mt][nt][1]);
        ov.z = f2bf(acc[mt][nt][2]); ov.w = f2bf(acc[mt][nt][3]);
        *(ushort4*)&vt[(size_t)col * SEQ + row0] = ov;
      }
  } else if (c_fp32) {
    float* Cf = (float*)C;
#pragma unroll
    for (int mt = 0; mt < 4; ++mt)
#pragma unroll
      for (int nt = 0; nt < 4; ++nt) {
        int col = n0 + wc + nt * 16 + l16;
#pragma unroll
        for (int r = 0; r < 4; ++r)
          Cf[(size_t)(m0 + wr + mt * 16 + quad * 4 + r) * ldc + col] = acc[mt][nt][r];
      }
  } else {
    unsigned short* Cb = (unsigned short*)C;
#pragma unroll
    for (int mt = 0; mt < 4; ++mt)
#pragma unroll
      for (int nt = 0; nt < 4; ++nt) {
        int col = n0 + wc + nt * 16 + l16;
#pragma unroll
        for (int r = 0; r < 4; ++r)
          Cb[(size_t)(m0 + wr + mt * 16 + quad * 4 + r) * ldc + col] = f2bf(acc[mt][nt][r]);
      }
  }
}

// ---------------- RoPE in-place on qkv (stride QLD), heads 0..39 = 32 q + 8 k ----------------
__global__ __launch_bounds__(256) void rope_kernel(unsigned short* __restrict__ QKV,
                                                   const float* __restrict__ cosb,
                                                   const float* __restrict__ sinb) {
  int idx = blockIdx.x * 256 + threadIdx.x;
  int i = idx & 63;
  int h = (idx >> 6) % 40;
  int s = idx / 2560;
  size_t base = (size_t)s * QLD + (size_t)h * 128;
  float q1 = bf2f(QKV[base + i]);
  float q2 = bf2f(QKV[base + i + 64]);
  float c1 = cosb[s * 128 + i],      s1 = sinb[s * 128 + i];
  float c2 = cosb[s * 128 + i + 64], s2 = sinb[s * 128 + i + 64];
  QKV[base + i]      = f2bf(q1 * c1 - q2 * s1);
  QKV[base + i + 64] = f2bf(q2 * c2 + q1 * s2);
}

// ---------------- flash attention: S^T formulation (QLD stride) ----------------
// R3: T14 async-STAGE split -- raw s_barrier (no vmcnt drain) + chunk c+1's
// global loads issued right after chunk c's ds_writes, so HBM latency rides
// under chunk c's compute. __syncthreads() would drain vmcnt at the barrier
// (the m97 stall); replaced with explicit lgkmcnt(0) + s_barrier.
// T5: setprio(1) around QK^T and PV MFMA clusters (2 blocks/CU, waves at
// independent phases -- the regime where setprio pays, m191).
__global__ __launch_bounds__(256) void flash_attn(const unsigned short* __restrict__ QKV,
                                                  const unsigned short* __restrict__ Vt_g,
                                                  unsigned short* __restrict__ AO) {
  __shared__ unsigned short Ks[64 * 136];
  __shared__ unsigned short Vs[128 * 72];
  __shared__ unsigned short Ps[4][32 * 68];

  const int h   = blockIdx.x;
  const int qt  = (int)gridDim.y - 1 - (int)blockIdx.y;
  const int kvh = h >> 2;
  const int tid  = threadIdx.x;
  const int w    = tid >> 6;
  const int lane = tid & 63;
  const int l16  = lane & 15;
  const int quad = lane >> 4;
  const int q0   = qt * 128;
  const int qrow_w = q0 + w * 32;

  short8 qf[2][4];
#pragma unroll
  for (int ntq = 0; ntq < 2; ++ntq) {
    const unsigned short* qp = QKV + (size_t)(qrow_w + ntq * 16 + l16) * QLD + h * HD + quad * 8;
#pragma unroll
    for (int ks = 0; ks < 4; ++ks) qf[ntq][ks] = *(const short8*)(qp + ks * 32);
  }

  f32x4 o[8][2];
#pragma unroll
  for (int i = 0; i < 8; ++i) { o[i][0] = (f32x4){0,0,0,0}; o[i][1] = (f32x4){0,0,0,0}; }
  float m_i[2] = {-3.0e38f, -3.0e38f}, l_i[2] = {0.f, 0.f};

  const int kr = tid >> 2, kcol0 = (tid & 3) * 32;
  const int vr = tid >> 1, vcol0 = (tid & 1) * 32;
  const unsigned short* kbase = QKV + KOFF + (size_t)kvh * HD + kcol0;
  const unsigned short* vbase = Vt_g + ((size_t)kvh * HD + vr) * SEQ + vcol0;

  const int nch = qt * 2 + 2;

  // prologue: issue chunk 0's loads
  short8 kv[4], vv[4];
#pragma unroll
  for (int u = 0; u < 4; ++u) kv[u] = *(const short8*)(kbase + (size_t)kr * QLD + u * 8);
#pragma unroll
  for (int u = 0; u < 4; ++u) vv[u] = *(const short8*)(vbase + u * 8);

  for (int c = 0; c < nch; ++c) {
    const int kc = c * 64;
    // WAR: all waves' LDS reads of the previous chunk were consumed by MFMAs
    // (compiler lgkm waits precede every use) before reaching this barrier.
    __builtin_amdgcn_s_barrier();
#pragma unroll
    for (int u = 0; u < 4; ++u) *(short8*)&Ks[kr * 136 + kcol0 + u * 8] = kv[u];
#pragma unroll
    for (int u = 0; u < 4; ++u) *(short8*)&Vs[vr * 72 + vcol0 + u * 8] = vv[u];
    // issue NEXT chunk's loads now -- they stay in flight under this chunk's
    // compute (raw barriers below do not drain vmcnt).
    if (c + 1 < nch) {
      const int kn = kc + 64;
#pragma unroll
      for (int u = 0; u < 4; ++u) kv[u] = *(const short8*)(kbase + (size_t)(kn + kr) * QLD + u * 8);
#pragma unroll
      for (int u = 0; u < 4; ++u) vv[u] = *(const short8*)(vbase + kn + u * 8);
    }
    asm volatile("s_waitcnt lgkmcnt(0)" ::: "memory");  // my ds_writes landed
    __builtin_amdgcn_s_barrier();                       // all writes visible

    if (kc <= qrow_w + 31) {
      f32x4 st[4][2];
#pragma unroll
      for (int mt = 0; mt < 4; ++mt) { st[mt][0] = (f32x4){0,0,0,0}; st[mt][1] = (f32x4){0,0,0,0}; }
      __builtin_amdgcn_s_setprio(1);
#pragma unroll
      for (int ks = 0; ks < 4; ++ks)
#pragma unroll
        for (int mt = 0; mt < 4; ++mt) {
          short8 ak = *(const short8*)&Ks[(mt * 16 + l16) * 136 + ks * 32 + quad * 8];
          st[mt][0] = __builtin_amdgcn_mfma_f32_16x16x32_bf16(ak, qf[0][ks], st[mt][0], 0, 0, 0);
          st[mt][1] = __builtin_amdgcn_mfma_f32_16x16x32_bf16(ak, qf[1][ks], st[mt][1], 0, 0, 0);
        }
      __builtin_amdgcn_s_setprio(0);

      float sc[4][2][4];
#pragma unroll
      for (int mt = 0; mt < 4; ++mt)
#pragma unroll
        for (int ntq = 0; ntq < 2; ++ntq) {
          int qr = qrow_w + ntq * 16 + l16;
#pragma unroll
          for (int r = 0; r < 4; ++r) {
            int key = kc + mt * 16 + quad * 4 + r;
            float v = st[mt][ntq][r] * SCALE;
            sc[mt][ntq][r] = (key <= qr) ? v : -__builtin_inff();
          }
        }
      float mx[2] = {-__builtin_inff(), -__builtin_inff()};
#pragma unroll
      for (int mt = 0; mt < 4; ++mt)
#pragma unroll
        for (int ntq = 0; ntq < 2; ++ntq)
#pragma unroll
          for (int r = 0; r < 4; ++r) mx[ntq] = fmaxf(mx[ntq], sc[mt][ntq][r]);
#pragma unroll
      for (int ntq = 0; ntq < 2; ++ntq) {
        mx[ntq] = fmaxf(mx[ntq], __shfl_xor(mx[ntq], 16, 64));
        mx[ntq] = fmaxf(mx[ntq], __shfl_xor(mx[ntq], 32, 64));
      }
      float al[2], mn[2];
#pragma unroll
      for (int ntq = 0; ntq < 2; ++ntq) {
        mn[ntq] = fmaxf(m_i[ntq], mx[ntq]);
        al[ntq] = __expf(m_i[ntq] - mn[ntq]);
        m_i[ntq] = mn[ntq];
      }

      float rs[2] = {0.f, 0.f};
      unsigned short* psw = &Ps[w][0];
#pragma unroll
      for (int mt = 0; mt < 4; ++mt)
#pragma unroll
        for (int ntq = 0; ntq < 2; ++ntq) {
          float p0 = __expf(sc[mt][ntq][0] - mn[ntq]);
          float p1 = __expf(sc[mt][ntq][1] - mn[ntq]);
          float p2 = __expf(sc[mt][ntq][2] - mn[ntq]);
          float p3 = __expf(sc[mt][ntq][3] - mn[ntq]);
          rs[ntq] += (p0 + p1) + (p2 + p3);
          ushort4 pk; pk.x = f2bf(p0); pk.y = f2bf(p1); pk.z = f2bf(p2); pk.w = f2bf(p3);
          *(ushort4*)&psw[(ntq * 16 + l16) * 68 + mt * 16 + quad * 4] = pk;
        }
#pragma unroll
      for (int ntq = 0; ntq < 2; ++ntq) {
        rs[ntq] += __shfl_xor(rs[ntq], 16, 64);
        rs[ntq] += __shfl_xor(rs[ntq], 32, 64);
        l_i[ntq] = l_i[ntq] * al[ntq] + rs[ntq];
      }
#pragma unroll
      for (int i = 0; i < 8; ++i) {
        o[i][0][0] *= al[0]; o[i][0][1] *= al[0]; o[i][0][2] *= al[0]; o[i][0][3] *= al[0];
        o[i][1][0] *= al[1]; o[i][1][1] *= al[1]; o[i][1][2] *= al[1]; o[i][1][3] *= al[1];
      }

#pragma unroll
      for (int ks = 0; ks < 2; ++ks) {
        short8 bp[2];
#pragma unroll
        for (int ntq = 0; ntq < 2; ++ntq) {
          union { ushort4 h[2]; short8 v; } u;
          const unsigned short* pp = &psw[(ntq * 16 + l16) * 68 + ks * 32 + quad * 8];
          u.h[0] = *(const ushort4*)(pp);
          u.h[1] = *(const ushort4*)(pp + 4);
          bp[ntq] = u.v;
        }
        __builtin_amdgcn_s_setprio(1);
#pragma unroll
        for (int mt = 0; mt < 8; ++mt) {
          short8 av = *(const short8*)&Vs[(mt * 16 + l16) * 72 + ks * 32 + quad * 8];
          o[mt][0] = __builtin_amdgcn_mfma_f32_16x16x32_bf16(av, bp[0], o[mt][0], 0, 0, 0);
          o[mt][1] = __builtin_amdgcn_mfma_f32_16x16x32_bf16(av, bp[1], o[mt][1], 0, 0, 0);
        }
        __builtin_amdgcn_s_setprio(0);
      }
    }
  }

  float inv[2] = {1.0f / l_i[0], 1.0f / l_i[1]};
#pragma unroll
  for (int mt = 0; mt < 8; ++mt)
#pragma unroll
    for (int ntq = 0; ntq < 2; ++ntq) {
      int qr = qrow_w + ntq * 16 + l16;
      int col = h * HD + mt * 16 + quad * 4;
      ushort4 ov;
      ov.x = f2bf(o[mt][ntq][0] * inv[ntq]);
      ov.y = f2bf(o[mt][ntq][1] * inv[ntq]);
      ov.z = f2bf(o[mt][ntq][2] * inv[ntq]);
      ov.w = f2bf(o[mt][ntq][3] * inv[ntq]);
      *(ushort4*)&AO[(size_t)qr * DM + col] = ov;
    }
}

extern "C" void kernel_launch(void* const* d_in, const int* in_sizes, int n_in,
                              void* d_out, int out_size, void* d_ws, size_t ws_size,
                              hipStream_t stream) {
  const float* hs   = (const float*)d_in[0];
  const float* cosb = (const float*)d_in[1];
  const float* sinb = (const float*)d_in[2];
  // d_in[3] attention_mask: all ones -> causal-only
  const float* wq = (const float*)d_in[4];
  const float* wk = (const float*)d_in[5];
  const float* wv = (const float*)d_in[6];
  const float* wo = (const float*)d_in[7];
  float* out = (float*)d_out;

  char* ws = (char*)d_ws;
  unsigned short* hsb   = (unsigned short*)(ws);                 // 16 MB
  unsigned short* wqkvT = (unsigned short*)(ws + (16u << 20));   // 48 MB
  unsigned short* woT   = (unsigned short*)(ws + (64u << 20));   // 32 MB
  unsigned short* qkv   = (unsigned short*)(ws + (96u << 20));   // 20 MB (2048 x 5120, Q+K only)
  unsigned short* ao    = (unsigned short*)(ws + (116u << 20));  // 16 MB
  unsigned short* Vt_g  = (unsigned short*)(ws + (132u << 20));  // 4 MB (distinct: gemm writes it while reading hsb)

  prep<<<8192 + 160 * 64, 256, 0, stream>>>(hs, wq, wk, wv, wo, hsb, wqkvT, woT);
  gemm_bt<<<dim3(NQKV / 128, SEQ / 128), 256, 0, stream>>>(hsb, wqkvT, qkv, Vt_g, SEQ, NQKV, DM, QLD, 0);
  rope_kernel<<<20480, 256, 0, stream>>>(qkv, cosb, sinb);
  flash_attn<<<dim3(NH, SEQ / 128), 256, 0, stream>>>(qkv, Vt_g, ao);
  gemm_bt<<<dim3(DM / 128, SEQ / 128), 256, 0, stream>>>(ao, woT, out, nullptr, SEQ, DM, DM, DM, 1);
}